// Round 5
// baseline (461.125 us; speedup 1.0000x reference)
//
#include <hip/hip_runtime.h>

// PiecewiseLinearEmbedding: out[i,t,:] = cumsum(W, axis=1)[:, x[i,t]] + b
//   x: (8192,200) int32 in [0,128]   W: (64,129) fp32   b: (64,) fp32
//   out: (8192,200,64) fp32 = 419.4 MB  -> pure streaming-write bound.
//
// R9: INSTRUMENTATION ROUND (deliberate dur regression).
// Five consecutive refuted predictions: R5 nt=neutral, R6 fusion=-3,
// R7 grid-stride=-7, R8 few-streams=+11. Embed is pinned at ~145us
// (2.9 TB/s stores) under every store-side variable: allocation policy,
// launch structure, macro address schedule, stream count. The fill does
// 6.2 TB/s with the SAME store instruction on the SAME arena. I have
// never seen embed's own counters -- it hides below the five ~270us
// poison fills in the rocprof top-5 -- and even the decomposition
// (420 = fill 270 + embed 145) assumes the fill is inside the timed
// graph. This round buys the counter row: R7's kernel with the hot loop
// run TWICE (memory clobber between passes blocks dead-store elim).
// Duration ~2x embed -> surfaces in top-5 with FETCH/WRITE/VALU/Occ/LDS.
// Predictions:
//   Case A (fill in graph, embed~143): dur -> ~550-565; embed row at
//     ~286us, WRITE_SIZE ~819,200 KB, FETCH_SIZE ~6,500 KB, conflicts ~0.
//   Case B (fill not in graph, embed~410): dur -> ~825, embed top-1.
//   Tripwires: FETCH >> 10 MB -> hidden output RMW; conflicts large ->
//     gather analysis wrong; VALUBusy > 60% -> issue-bound; low Occ ->
//     waves not resident.
// Next round reverts the double pass and acts on the counters.

constexpr int F1   = 129;              // NUM_FEATURE + 1 bins
constexpr int D    = 64;               // VECTOR_DIM
constexpr int ROWS = 8192 * 200;       // 1,638,400 lookup rows
constexpr int TBL_F = F1 * D;          // 8,256 floats (33,024 B)
constexpr int TBL4  = TBL_F / 4;       // 2,064 float4

constexpr int BLOCKS = 1024;
constexpr int TPB    = 512;            // 4 blocks/CU -> 32 waves/CU (100%)
constexpr int G      = BLOCKS * TPB;   // 524,288 threads = 2^19
constexpr int Q_TOT  = ROWS * D / 4;   // 26,214,400 float4 total
constexpr int ITERS  = Q_TOT / G;      // 50 exactly
constexpr int ROWS_PER_BLOCK = ROWS / BLOCKS;   // 1600 (50 chunks x 32 rows)
constexpr int ROWS_PER_ITER  = G / 16;          // 32,768 rows per sweep window

typedef float floatx4 __attribute__((ext_vector_type(4)));

__global__ __launch_bounds__(TPB, 8) void embed_fused_kernel(
        const int*   __restrict__ x,
        const float* __restrict__ W,
        const float* __restrict__ b,
        float*       __restrict__ out) {
    __shared__ floatx4 lds_tbl[TBL4];          // 33,024 B, j-major table
    __shared__ int     lds_x[ROWS_PER_BLOCK];  //  6,400 B  (39,424 B -> 4 blk/CU)
    float* tblf = (float*)lds_tbl;

    // Stage this block's 50 x-chunks (32 consecutive rows each, at
    // 32,768-row stride): lds_x[it*32 + r] = x[it*32768 + blockIdx.x*32 + r].
    const int xbase = blockIdx.x * 32;
    for (int i = threadIdx.x; i < ROWS_PER_BLOCK; i += TPB)
        lds_x[i] = x[(i >> 5) * ROWS_PER_ITER + xbase + (i & 31)];

    // Wave 0: build the cumsum table (lane-per-row scan of L2-hot W,
    // 8-deep load batching; LDS writes [j*64+d] bank d%32, conflict-free).
    if (threadIdx.x < D) {
        const int d = threadIdx.x;
        const float* wrow = W + d * F1;
        float acc = b[d];
        int j = 0;
#pragma unroll 1
        for (int c = 0; c < 16; ++c) {         // 16 chunks of 8 = 128
            float v[8];
#pragma unroll
            for (int i = 0; i < 8; ++i) v[i] = wrow[j + i];   // independent loads
#pragma unroll
            for (int i = 0; i < 8; ++i) { acc += v[i]; tblf[(j + i) * D + d] = acc; }
            j += 8;
        }
        acc += wrow[128];                      // tail bin
        tblf[128 * D + d] = acc;
    }
    __syncthreads();

    // Hot loop, RUN TWICE (instrumentation): grid-stride dense sweep,
    // iteration it writes the contiguous 8 MB window [it*G,(it+1)*G).
    // Pass 2 rewrites identical values; memory clobber prevents DCE of
    // pass 1. Gather: 16 lanes/addr broadcast; b128 reads uniform over
    // banks (xi*64 words % 32 == 0), conflict-free.
    floatx4* out4 = (floatx4*)out;
    const int base = blockIdx.x * TPB + threadIdx.x;
    const int xrow = threadIdx.x >> 4;
    const int quad = threadIdx.x & 15;
#pragma unroll 1
    for (int pass = 0; pass < 2; ++pass) {
#pragma unroll 5
        for (int it = 0; it < ITERS; ++it) {
            int q  = it * G + base;              // < 2^25, int-safe
            int xi = lds_x[it * 32 + xrow];      // broadcast (16 lanes/addr)
            floatx4 v = lds_tbl[xi * 16 + quad];
            out4[q] = v;                         // wave: 1 KB contiguous store
        }
        asm volatile("" ::: "memory");           // pass-1 stores stay live
    }
}

extern "C" void kernel_launch(void* const* d_in, const int* in_sizes, int n_in,
                              void* d_out, int out_size, void* d_ws, size_t ws_size,
                              hipStream_t stream) {
    const int*   x = (const int*)  d_in[0];
    const float* W = (const float*)d_in[1];
    const float* b = (const float*)d_in[2];
    float* out = (float*)d_out;
    (void)d_ws; (void)ws_size;

    embed_fused_kernel<<<BLOCKS, TPB, 0, stream>>>(x, W, b, out);
}

// Round 7
// 412.507 us; speedup vs baseline: 1.1179x; 1.1179x over previous
//
#include <hip/hip_runtime.h>

// PiecewiseLinearEmbedding: out[i,t,:] = cumsum(W, axis=1)[:, x[i,t]] + b
//   x: (8192,200) int32 in [0,128]   W: (64,129) fp32   b: (64,) fp32
//   out: (8192,200,64) fp32 = 419.4 MB streaming-write kernel.
//
// R11 == R10 == R7 (resubmit; R10 hit "MI355X container failed twice" --
// infra failure, no data; this exact body passed at 412.9 us in R7).
// Accounting (established by the R9 double-store instrumentation round):
//   dur 413 = poison fill ~270 (rocprof top-5, harness)
//           + ~90 us of tiny restore dispatches + graph gaps (harness
//             reset(); per rocprof.md these never show in top-5)
//           + embed ~53 us.
// Store sweep's same-conditions floor ~48 us (R9 marginal pass): 419 MB
// transits L2/L3 once; the dirty tail in Infinity Cache is overwritten
// by the next iteration's poison fill before writeback, eliding most HBM
// write traffic. Kernel-owned headroom ~5 us (~1% of dur) = noise ->
// roofline once this measurement reproduces.
// R5-R8 retrospective: they optimized a 53 us kernel against a phantom
// 143 us model; the 90 us residual was fixed harness overhead.
//   R5 nt stores: +2.5 (weakens L3 retention that elides writeback)
//   R6 fusion: -3 (real launch overhead, kept)
//   R7 grid-stride sweep: -7 (best; kept)
//   R8 few-streams: +11 (latency exposure at 4 waves/CU)

constexpr int F1   = 129;              // NUM_FEATURE + 1 bins
constexpr int D    = 64;               // VECTOR_DIM
constexpr int ROWS = 8192 * 200;       // 1,638,400 lookup rows
constexpr int TBL_F = F1 * D;          // 8,256 floats (33,024 B)
constexpr int TBL4  = TBL_F / 4;       // 2,064 float4

constexpr int BLOCKS = 1024;
constexpr int TPB    = 512;            // 4 blocks/CU -> 32 waves/CU (100%)
constexpr int G      = BLOCKS * TPB;   // 524,288 threads = 2^19
constexpr int Q_TOT  = ROWS * D / 4;   // 26,214,400 float4 total
constexpr int ITERS  = Q_TOT / G;      // 50 exactly
constexpr int ROWS_PER_BLOCK = ROWS / BLOCKS;   // 1600 (50 chunks x 32 rows)
constexpr int ROWS_PER_ITER  = G / 16;          // 32,768 rows per sweep window

typedef float floatx4 __attribute__((ext_vector_type(4)));

__global__ __launch_bounds__(TPB, 8) void embed_fused_kernel(
        const int*   __restrict__ x,
        const float* __restrict__ W,
        const float* __restrict__ b,
        float*       __restrict__ out) {
    __shared__ floatx4 lds_tbl[TBL4];          // 33,024 B, j-major table
    __shared__ int     lds_x[ROWS_PER_BLOCK];  //  6,400 B  (39,424 B -> 4 blk/CU)
    float* tblf = (float*)lds_tbl;

    // Stage this block's 50 x-chunks (32 consecutive rows each, at
    // 32,768-row stride): lds_x[it*32 + r] = x[it*32768 + blockIdx.x*32 + r].
    // Per 32-element chunk the global read is a contiguous 128 B segment.
    const int xbase = blockIdx.x * 32;
    for (int i = threadIdx.x; i < ROWS_PER_BLOCK; i += TPB)
        lds_x[i] = x[(i >> 5) * ROWS_PER_ITER + xbase + (i & 31)];

    // Wave 0: build the cumsum table. Lane d scans W row d from global
    // (33 KB); loads batched 8-deep so the only serial chain is
    // 129 v_add_f32. LDS writes [j*64+d]: lanes span d at fixed j ->
    // bank d%32, 2-way, conflict-free.
    if (threadIdx.x < D) {
        const int d = threadIdx.x;
        const float* wrow = W + d * F1;
        float acc = b[d];
        int j = 0;
#pragma unroll 1
        for (int c = 0; c < 16; ++c) {         // 16 chunks of 8 = 128
            float v[8];
#pragma unroll
            for (int i = 0; i < 8; ++i) v[i] = wrow[j + i];   // independent loads
#pragma unroll
            for (int i = 0; i < 8; ++i) { acc += v[i]; tblf[(j + i) * D + d] = acc; }
            j += 8;
        }
        acc += wrow[128];                      // tail bin
        tblf[128 * D + d] = acc;
    }
    __syncthreads();

    // Hot loop: grid-stride dense sweep. Iteration it: whole device writes
    // the contiguous 8 MB window [it*G, (it+1)*G) of float4s.
    //   q>>4  = it*32768 + blockIdx.x*32 + (tid>>4)  -> lds_x[it*32+(tid>>4)]
    //   q&15  = tid&15                                (G, blk offs mult of 16)
    // Gather: 16 lanes/addr broadcast on lds_x; lds_tbl b128 read uniform
    // over banks (xi*64 words % 32 == 0), conflict-free.
    floatx4* out4 = (floatx4*)out;
    const int base = blockIdx.x * TPB + threadIdx.x;
    const int xrow = threadIdx.x >> 4;
    const int quad = threadIdx.x & 15;
#pragma unroll 5
    for (int it = 0; it < ITERS; ++it) {
        int q  = it * G + base;              // < 2^25, int-safe
        int xi = lds_x[it * 32 + xrow];      // broadcast (16 lanes/addr)
        floatx4 v = lds_tbl[xi * 16 + quad];
        out4[q] = v;                         // wave: 1 KB contiguous store
    }
}

extern "C" void kernel_launch(void* const* d_in, const int* in_sizes, int n_in,
                              void* d_out, int out_size, void* d_ws, size_t ws_size,
                              hipStream_t stream) {
    const int*   x = (const int*)  d_in[0];
    const float* W = (const float*)d_in[1];
    const float* b = (const float*)d_in[2];
    float* out = (float*)d_out;
    (void)d_ws; (void)ws_size;

    embed_fused_kernel<<<BLOCKS, TPB, 0, stream>>>(x, W, b, out);
}